// Round 7
// baseline (183.413 us; speedup 1.0000x reference)
//
#include <hip/hip_runtime.h>
#include <stdint.h>

typedef unsigned short u16;
typedef short bf16x8 __attribute__((ext_vector_type(8)));
typedef unsigned short u16x4 __attribute__((ext_vector_type(4)));
typedef float f32x4 __attribute__((ext_vector_type(4)));

#define NROW 4096
#define LDW 72        // LDS row stride (u16) for 64x64 W^T tile
#define SLICE 262144  // 4096*64 floats per partial slice
#define NSPLIT 32     // split-k over i (2048 blocks -> ~6 blocks/CU + turnover)

// round-to-nearest-even float -> bf16 bits (used where fidelity matters: x, U)
__device__ __forceinline__ u16 f2bf(float f) {
  uint32_t u = __float_as_uint(f);
  u = (u + 0x7fffu + ((u >> 16) & 1u)) >> 16;
  return (u16)u;
}

// truncating float -> bf16 (weights only: <=0.8% downward bias on num AND den, cancels)
__device__ __forceinline__ u16 f2bf_t(float f) {
  return (u16)(__float_as_uint(f) >> 16);
}

__device__ __forceinline__ f32x4 mfma16(bf16x8 a, bf16x8 b, f32x4 c) {
  return __builtin_amdgcn_mfma_f32_16x16x32_bf16(a, b, c, 0, 0, 0);
}

__device__ __forceinline__ bf16x8 ld8(const u16* p) {
  return *reinterpret_cast<const bf16x8*>(p);
}

// single v_sqrt_f32 (args well-scaled: 1e-6 .. ~300)
__device__ __forceinline__ float fast_sqrt(float x) {
  return __builtin_amdgcn_sqrtf(x);
}

// ---------------- prep: sq[i], xb, xT; also zero-init maxslots ----------------
__global__ __launch_bounds__(256) void prep_kernel(const float* __restrict__ x,
                                                   u16* __restrict__ xb, u16* __restrict__ xT,
                                                   float* __restrict__ sq,
                                                   float* __restrict__ maxslots) {
  __shared__ u16 lt[64 * 68];
  const int w = threadIdx.x >> 6, lane = threadIdx.x & 63;
  const int r0 = blockIdx.x * 64;
  if (blockIdx.x == 0 && threadIdx.x < 64) maxslots[threadIdx.x * 16] = 0.f;
#pragma unroll
  for (int rr = 0; rr < 16; ++rr) {
    int rl = w * 16 + rr;
    int row = r0 + rl;
    float v = x[row * 64 + lane];
    u16 b = f2bf(v);
    xb[row * 64 + lane] = b;
    lt[lane * 68 + rl] = b;
    float s = v * v;
#pragma unroll
    for (int o = 1; o < 64; o <<= 1) s += __shfl_xor(s, o);
    if (lane == 0) sq[row] = s;
  }
  __syncthreads();
#pragma unroll
  for (int cc = 0; cc < 16; ++cc) {
    int c = w * 16 + cc;
    xT[c * NROW + r0 + lane] = lt[c * 68 + lane];
  }
}

// ---------------- pass1: max d2; A-frag reuse over 4 j-tiles; 1 atomic/block ----------------
__global__ __launch_bounds__(256) void pass1_max(const u16* __restrict__ xb,
                                                 const float* __restrict__ sq,
                                                 float* __restrict__ maxslots) {
  __shared__ float red[4];
  int w = threadIdx.x >> 6, lane = threadIdx.x & 63;
  int l16 = lane & 15, quad = lane >> 4;
  int ti = blockIdx.x;
  int i0 = ti * 64 + w * 16;
  bf16x8 a0 = ld8(xb + (i0 + l16) * 64 + quad * 8);
  bf16x8 a1 = ld8(xb + (i0 + l16) * 64 + 32 + quad * 8);
  float sqi[4];
#pragma unroll
  for (int r = 0; r < 4; ++r) sqi[r] = sq[i0 + quad * 4 + r];
  float m = 0.f;
  const int jbase = blockIdx.y * 256;
#pragma unroll
  for (int jb = 0; jb < 4; ++jb) {
    int j0 = jbase + jb * 64;
#pragma unroll
    for (int jt = 0; jt < 4; ++jt) {
      int jr = j0 + jt * 16 + l16;
      bf16x8 b0 = ld8(xb + jr * 64 + quad * 8);
      bf16x8 b1 = ld8(xb + jr * 64 + 32 + quad * 8);
      f32x4 g = {0.f, 0.f, 0.f, 0.f};
      g = mfma16(a0, b0, g);
      g = mfma16(a1, b1, g);
      float sj = sq[jr];
#pragma unroll
      for (int r = 0; r < 4; ++r) m = fmaxf(m, fmaf(-2.f, g[r], sqi[r] + sj));
    }
  }
  m = fmaxf(m, 0.f);
#pragma unroll
  for (int o = 1; o < 64; o <<= 1) m = fmaxf(m, __shfl_xor(m, o));
  if (lane == 0) red[w] = m;
  __syncthreads();
  if (threadIdx.x == 0) {
    m = fmaxf(fmaxf(red[0], red[1]), fmaxf(red[2], red[3]));
    atomicMax((int*)&maxslots[ti * 16], __float_as_int(m));
  }
}

// ---------------- pass2: alpha weights + mu numerator partials ----------------
__global__ __launch_bounds__(256) void pass2_kernel(
    const u16* __restrict__ xb, const u16* __restrict__ xT, const float* __restrict__ sq,
    const float* __restrict__ maxslots, const float* __restrict__ r0in,
    float* __restrict__ mu_part, float* __restrict__ s_part) {
  __shared__ u16 ldsw[2][64 * LDW];
  __shared__ float sred[4][64];
  const int tid = threadIdx.x, w = tid >> 6, lane = tid & 63;
  const int l16 = lane & 15, quad = lane >> 4;
  const int j0 = blockIdx.x * 64;
  const int ibase = blockIdx.y * 128;

  float md = 0.f;
#pragma unroll
  for (int k = 0; k < 64; ++k) md = fmaxf(md, maxslots[k * 16]);
  const float r0c = fminf(r0in[0], fast_sqrt(md));
  const float r0sq = r0c * r0c;
  const float invr0sq = 1.f / r0sq;

  float sqj[4];
  bf16x8 xj[4][2];
#pragma unroll
  for (int jt = 0; jt < 4; ++jt) {
    int jr = j0 + jt * 16 + l16;
    sqj[jt] = sq[jr];
    xj[jt][0] = ld8(xb + jr * 64 + quad * 8);
    xj[jt][1] = ld8(xb + jr * 64 + 32 + quad * 8);
  }
  f32x4 zero4 = {0.f, 0.f, 0.f, 0.f};
  f32x4 acc[4];
#pragma unroll
  for (int pt = 0; pt < 4; ++pt) acc[pt] = zero4;
  float sa[4] = {0.f, 0.f, 0.f, 0.f};

#pragma unroll
  for (int s = 0; s < 2; ++s) {
    u16* buf = &ldsw[s & 1][0];
    const int ib = ibase + s * 64;
    const int ir = ib + w * 16;
    bf16x8 a0 = ld8(xb + (ir + l16) * 64 + quad * 8);
    bf16x8 a1 = ld8(xb + (ir + l16) * 64 + 32 + quad * 8);
    float sqi[4];
#pragma unroll
    for (int r = 0; r < 4; ++r) sqi[r] = sq[ir + quad * 4 + r];
    // pair-hoisted Gram MFMAs for ILP
#pragma unroll
    for (int jp = 0; jp < 2; ++jp) {
      const int jt0 = jp * 2, jt1 = jp * 2 + 1;
      f32x4 g0 = zero4, g1 = zero4;
      g0 = mfma16(a0, xj[jt0][0], g0);
      g1 = mfma16(a0, xj[jt1][0], g1);
      g0 = mfma16(a1, xj[jt0][1], g0);
      g1 = mfma16(a1, xj[jt1][1], g1);
      u16x4 pk0, pk1;
#pragma unroll
      for (int r = 0; r < 4; ++r) {
        float d2a = fmaxf(fmaf(-2.f, g0[r], sqi[r] + sqj[jt0]), 0.f);
        float ba = fmaxf(fmaf(-d2a, invr0sq, 1.f), 0.f);
        float wa = ba * ba * ba;
        sa[jt0] += wa;
        pk0[r] = f2bf_t(wa);
        float d2b = fmaxf(fmaf(-2.f, g1[r], sqi[r] + sqj[jt1]), 0.f);
        float bb = fmaxf(fmaf(-d2b, invr0sq, 1.f), 0.f);
        float wb = bb * bb * bb;
        sa[jt1] += wb;
        pk1[r] = f2bf_t(wb);
      }
      *reinterpret_cast<u16x4*>(&buf[(jt0 * 16 + l16) * LDW + w * 16 + quad * 4]) = pk0;
      *reinterpret_cast<u16x4*>(&buf[(jt1 * 16 + l16) * LDW + w * 16 + quad * 4]) = pk1;
    }
    __syncthreads();
    bf16x8 aw0 = *reinterpret_cast<const bf16x8*>(&buf[(w * 16 + l16) * LDW + quad * 8]);
    bf16x8 aw1 = *reinterpret_cast<const bf16x8*>(&buf[(w * 16 + l16) * LDW + 32 + quad * 8]);
#pragma unroll
    for (int pt = 0; pt < 4; ++pt) {
      const u16* xp = xT + (pt * 16 + l16) * NROW + ib + quad * 8;
      acc[pt] = mfma16(aw0, ld8(xp), acc[pt]);
      acc[pt] = mfma16(aw1, ld8(xp + 32), acc[pt]);
    }
  }
  float* mp = mu_part + (size_t)blockIdx.y * SLICE;
#pragma unroll
  for (int pt = 0; pt < 4; ++pt)
#pragma unroll
    for (int r = 0; r < 4; ++r)
      mp[(j0 + w * 16 + quad * 4 + r) * 64 + pt * 16 + l16] = acc[pt][r];
#pragma unroll
  for (int jt = 0; jt < 4; ++jt) {
    float v = sa[jt];
    v += __shfl_xor(v, 16);
    v += __shfl_xor(v, 32);
    if (lane < 16) sred[w][jt * 16 + lane] = v;
  }
  __syncthreads();
  if (tid < 64)
    s_part[blockIdx.y * NROW + j0 + tid] =
        sred[0][tid] + sred[1][tid] + sred[2][tid] + sred[3][tid];
}

// ---------------- finish_mu: reduce partials; U, ||U||^2, t ----------------
__global__ __launch_bounds__(256) void finish_mu_kernel(
    const float* __restrict__ x, const float* __restrict__ mu_part,
    const float* __restrict__ s_part, u16* __restrict__ ub, float* __restrict__ un2,
    float* __restrict__ tvec) {
  int row = blockIdx.x * 4 + (threadIdx.x >> 6);
  int lane = threadIdx.x & 63;
  float num = 0.f, den = 0.f;
#pragma unroll
  for (int y = 0; y < NSPLIT; ++y) {
    num += mu_part[(size_t)y * SLICE + row * 64 + lane];
    den += s_part[y * NROW + row];
  }
  float xv = x[row * 64 + lane];
  float m = num / den;
  if (m != m) m = xv;
  float U = xv - m;
  ub[row * 64 + lane] = f2bf(U);
  float a = U * U;
  float b = xv * U;
#pragma unroll
  for (int o = 1; o < 64; o <<= 1) {
    a += __shfl_xor(a, o);
    b += __shfl_xor(b, o);
  }
  if (lane == 0) {
    un2[row] = a;
    tvec[row] = b;
  }
}

// ---------------- pass3: beta weights + e_Z numerator partials ----------------
__global__ __launch_bounds__(256) void pass3_kernel(
    const u16* __restrict__ xb, const u16* __restrict__ xT, const u16* __restrict__ ub,
    const float* __restrict__ sq, const float* __restrict__ tvec, const float* __restrict__ un2,
    const float* __restrict__ maxslots, const float* __restrict__ r1in,
    const float* __restrict__ r2in, float* __restrict__ ez_part, float* __restrict__ s_part) {
  __shared__ u16 ldsw[2][64 * LDW];
  __shared__ float sred[4][64];
  const int tid = threadIdx.x, w = tid >> 6, lane = tid & 63;
  const int l16 = lane & 15, quad = lane >> 4;
  const int j0 = blockIdx.x * 64;
  const int ibase = blockIdx.y * 128;

  float md = 0.f;
#pragma unroll
  for (int k = 0; k < 64; ++k) md = fmaxf(md, maxslots[k * 16]);
  const float mdist = fast_sqrt(md);
  const float r1c = fminf(r1in[0], mdist);
  const float r2c = fminf(r2in[0], mdist);
  const float i1x2 = 2.f / r1c;
  const float i2x2 = 2.f / r2c;

  float sqj[4], tj[4], u2j[4];
  bf16x8 xj[4][2], uj[4][2];
#pragma unroll
  for (int jt = 0; jt < 4; ++jt) {
    int jr = j0 + jt * 16 + l16;
    sqj[jt] = sq[jr];
    tj[jt] = tvec[jr];
    u2j[jt] = un2[jr];
    xj[jt][0] = ld8(xb + jr * 64 + quad * 8);
    xj[jt][1] = ld8(xb + jr * 64 + 32 + quad * 8);
    uj[jt][0] = ld8(ub + jr * 64 + quad * 8);
    uj[jt][1] = ld8(ub + jr * 64 + 32 + quad * 8);
  }
  f32x4 zero4 = {0.f, 0.f, 0.f, 0.f};
  f32x4 acc[4];
#pragma unroll
  for (int pt = 0; pt < 4; ++pt) acc[pt] = zero4;
  float sb[4] = {0.f, 0.f, 0.f, 0.f};

#pragma unroll
  for (int s = 0; s < 2; ++s) {
    u16* buf = &ldsw[s & 1][0];
    const int ib = ibase + s * 64;
    const int ir = ib + w * 16;
    bf16x8 a0 = ld8(xb + (ir + l16) * 64 + quad * 8);
    bf16x8 a1 = ld8(xb + (ir + l16) * 64 + 32 + quad * 8);
    float sqi[4];
#pragma unroll
    for (int r = 0; r < 4; ++r) sqi[r] = sq[ir + quad * 4 + r];
    // pair-hoisted: 8 independent MFMAs in flight, then two epilogues
#pragma unroll
    for (int jp = 0; jp < 2; ++jp) {
      const int jt0 = jp * 2, jt1 = jp * 2 + 1;
      f32x4 gxx0 = zero4, gxu0 = zero4, gxx1 = zero4, gxu1 = zero4;
      gxx0 = mfma16(a0, xj[jt0][0], gxx0);
      gxx1 = mfma16(a0, xj[jt1][0], gxx1);
      gxu0 = mfma16(a0, uj[jt0][0], gxu0);
      gxu1 = mfma16(a0, uj[jt1][0], gxu1);
      gxx0 = mfma16(a1, xj[jt0][1], gxx0);
      gxx1 = mfma16(a1, xj[jt1][1], gxx1);
      gxu0 = mfma16(a1, uj[jt0][1], gxu0);
      gxu1 = mfma16(a1, uj[jt1][1], gxu1);
      u16x4 pk0, pk1;
#pragma unroll
      for (int r = 0; r < 4; ++r) {
        float d2a = fmaxf(fmaf(-2.f, gxx0[r], sqi[r] + sqj[jt0]), 0.f);
        float ca = gxu0[r] - tj[jt0];
        float du2a = fmaxf(ca * ca * u2j[jt0], 1e-6f);
        float dv2a = fmaxf(d2a - du2a, 1e-6f);
        float dua = fast_sqrt(du2a);
        float dva = fast_sqrt(dv2a);
        float q1a = fminf(fmaxf(fmaf(dva, i1x2, -1.f), 0.f), 1.f);
        float b1a = fmaf(-q1a, q1a, 1.f);
        float w1a = b1a * b1a * b1a;
        float q2a = fminf(fmaxf(fmaf(dua, i2x2, -1.f), 0.f), 1.f);
        float b2a = fmaf(-q2a, q2a, 1.f);
        float w2a = b2a * b2a * b2a;
        float wva = w1a * w2a;
        sb[jt0] += wva;
        pk0[r] = f2bf_t(wva);
        float d2b = fmaxf(fmaf(-2.f, gxx1[r], sqi[r] + sqj[jt1]), 0.f);
        float cb = gxu1[r] - tj[jt1];
        float du2b = fmaxf(cb * cb * u2j[jt1], 1e-6f);
        float dv2b = fmaxf(d2b - du2b, 1e-6f);
        float dub = fast_sqrt(du2b);
        float dvb = fast_sqrt(dv2b);
        float q1b = fminf(fmaxf(fmaf(dvb, i1x2, -1.f), 0.f), 1.f);
        float b1b = fmaf(-q1b, q1b, 1.f);
        float w1b = b1b * b1b * b1b;
        float q2b = fminf(fmaxf(fmaf(dub, i2x2, -1.f), 0.f), 1.f);
        float b2b = fmaf(-q2b, q2b, 1.f);
        float w2b = b2b * b2b * b2b;
        float wvb = w1b * w2b;
        sb[jt1] += wvb;
        pk1[r] = f2bf_t(wvb);
      }
      *reinterpret_cast<u16x4*>(&buf[(jt0 * 16 + l16) * LDW + w * 16 + quad * 4]) = pk0;
      *reinterpret_cast<u16x4*>(&buf[(jt1 * 16 + l16) * LDW + w * 16 + quad * 4]) = pk1;
    }
    __syncthreads();
    bf16x8 aw0 = *reinterpret_cast<const bf16x8*>(&buf[(w * 16 + l16) * LDW + quad * 8]);
    bf16x8 aw1 = *reinterpret_cast<const bf16x8*>(&buf[(w * 16 + l16) * LDW + 32 + quad * 8]);
#pragma unroll
    for (int pt = 0; pt < 4; ++pt) {
      const u16* xp = xT + (pt * 16 + l16) * NROW + ib + quad * 8;
      acc[pt] = mfma16(aw0, ld8(xp), acc[pt]);
      acc[pt] = mfma16(aw1, ld8(xp + 32), acc[pt]);
    }
  }
  float* ep = ez_part + (size_t)blockIdx.y * SLICE;
#pragma unroll
  for (int pt = 0; pt < 4; ++pt)
#pragma unroll
    for (int r = 0; r < 4; ++r)
      ep[(j0 + w * 16 + quad * 4 + r) * 64 + pt * 16 + l16] = acc[pt][r];
#pragma unroll
  for (int jt = 0; jt < 4; ++jt) {
    float v = sb[jt];
    v += __shfl_xor(v, 16);
    v += __shfl_xor(v, 32);
    if (lane < 16) sred[w][jt * 16 + lane] = v;
  }
  __syncthreads();
  if (tid < 64)
    s_part[blockIdx.y * NROW + j0 + tid] =
        sred[0][tid] + sred[1][tid] + sred[2][tid] + sred[3][tid];
}

// ---------------- finish: e_Z = reduce partials, NaN -> x ----------------
__global__ __launch_bounds__(256) void finish_kernel(const float* __restrict__ x,
                                                     const float* __restrict__ ez_part,
                                                     const float* __restrict__ s_part,
                                                     float* __restrict__ out) {
  int row = blockIdx.x * 4 + (threadIdx.x >> 6);
  int lane = threadIdx.x & 63;
  float num = 0.f, den = 0.f;
#pragma unroll
  for (int y = 0; y < NSPLIT; ++y) {
    num += ez_part[(size_t)y * SLICE + row * 64 + lane];
    den += s_part[y * NROW + row];
  }
  float xv = x[row * 64 + lane];
  float v = num / den;
  if (v != v) v = xv;
  out[row * 64 + lane] = v;
}

extern "C" void kernel_launch(void* const* d_in, const int* in_sizes, int n_in,
                              void* d_out, int out_size, void* d_ws, size_t ws_size,
                              hipStream_t stream) {
  (void)in_sizes; (void)n_in; (void)out_size;
  const float* x = (const float*)d_in[0];
  const float* r0 = (const float*)d_in[1];
  const float* r1 = (const float*)d_in[2];
  const float* r2 = (const float*)d_in[3];
  float* out = (float*)d_out;
  char* ws = (char*)d_ws;

  u16* xb = (u16*)(ws);                              // 512 KB
  u16* xT = (u16*)(ws + (512 << 10));                // 512 KB
  u16* ub = (u16*)(ws + (1024 << 10));               // 512 KB
  float* sq = (float*)(ws + (1536 << 10));           // 16 KB
  float* tv = (float*)(ws + (1552 << 10));           // 16 KB
  float* u2 = (float*)(ws + (1568 << 10));           // 16 KB
  float* maxslots = (float*)(ws + (1584 << 10));     // 4 KB
  float* s_part_a = (float*)(ws + (1588 << 10));     // 512 KB (32 x 4096 fl)
  float* s_part_b = (float*)(ws + (2100 << 10));     // 512 KB
  float* part = (float*)(ws + (2612 << 10));         // 32 MB (aliased mu/ez partials)
  size_t need = ((size_t)2612 << 10) + ((size_t)32 << 20);
  if (ws_size < need) return;

  prep_kernel<<<64, 256, 0, stream>>>(x, xb, xT, sq, maxslots);
  pass1_max<<<dim3(64, 16), 256, 0, stream>>>(xb, sq, maxslots);
  pass2_kernel<<<dim3(64, NSPLIT), 256, 0, stream>>>(xb, xT, sq, maxslots, r0, part, s_part_a);
  finish_mu_kernel<<<1024, 256, 0, stream>>>(x, part, s_part_a, ub, u2, tv);
  pass3_kernel<<<dim3(64, NSPLIT), 256, 0, stream>>>(xb, xT, ub, sq, tv, u2, maxslots, r1, r2,
                                                     part, s_part_b);
  finish_kernel<<<1024, 256, 0, stream>>>(x, part, s_part_b, out);
}

// Round 8
// 166.839 us; speedup vs baseline: 1.0993x; 1.0993x over previous
//
#include <hip/hip_runtime.h>
#include <stdint.h>

typedef unsigned short u16;
typedef short bf16x8 __attribute__((ext_vector_type(8)));
typedef unsigned short u16x4 __attribute__((ext_vector_type(4)));
typedef float f32x4 __attribute__((ext_vector_type(4)));

#define NROW 4096
#define LDW 72        // LDS row stride (u16) for 64x64 W^T tile
#define SLICE 262144  // 4096*64 floats per partial slice
#define NSPLIT 16     // split-k over i (1024 blocks; 32 regressed: +64MB partial traffic)

// round-to-nearest-even float -> bf16 bits (x, U: fidelity matters)
__device__ __forceinline__ u16 f2bf(float f) {
  uint32_t u = __float_as_uint(f);
  u = (u + 0x7fffu + ((u >> 16) & 1u)) >> 16;
  return (u16)u;
}

// truncating float -> bf16 (weights only: bias cancels between num and den)
__device__ __forceinline__ u16 f2bf_t(float f) {
  return (u16)(__float_as_uint(f) >> 16);
}

__device__ __forceinline__ f32x4 mfma16(bf16x8 a, bf16x8 b, f32x4 c) {
  return __builtin_amdgcn_mfma_f32_16x16x32_bf16(a, b, c, 0, 0, 0);
}

__device__ __forceinline__ bf16x8 ld8(const u16* p) {
  return *reinterpret_cast<const bf16x8*>(p);
}

// single v_sqrt_f32 (args well-scaled: 1e-6 .. ~300)
__device__ __forceinline__ float fast_sqrt(float x) {
  return __builtin_amdgcn_sqrtf(x);
}

// ---------------- prep: sq[i], xb, xT; also zero-init maxslots ----------------
__global__ __launch_bounds__(256) void prep_kernel(const float* __restrict__ x,
                                                   u16* __restrict__ xb, u16* __restrict__ xT,
                                                   float* __restrict__ sq,
                                                   float* __restrict__ maxslots) {
  __shared__ u16 lt[64 * 68];
  const int w = threadIdx.x >> 6, lane = threadIdx.x & 63;
  const int r0 = blockIdx.x * 64;
  if (blockIdx.x == 0 && threadIdx.x < 64) maxslots[threadIdx.x * 16] = 0.f;
#pragma unroll
  for (int rr = 0; rr < 16; ++rr) {
    int rl = w * 16 + rr;
    int row = r0 + rl;
    float v = x[row * 64 + lane];
    u16 b = f2bf(v);
    xb[row * 64 + lane] = b;
    lt[lane * 68 + rl] = b;
    float s = v * v;
#pragma unroll
    for (int o = 1; o < 64; o <<= 1) s += __shfl_xor(s, o);
    if (lane == 0) sq[row] = s;
  }
  __syncthreads();
#pragma unroll
  for (int cc = 0; cc < 16; ++cc) {
    int c = w * 16 + cc;
    xT[c * NROW + r0 + lane] = lt[c * 68 + lane];
  }
}

// ---------------- pass1: max d2; A-frag reuse over 4 j-tiles; 1 atomic/block ----------------
__global__ __launch_bounds__(256) void pass1_max(const u16* __restrict__ xb,
                                                 const float* __restrict__ sq,
                                                 float* __restrict__ maxslots) {
  __shared__ float red[4];
  int w = threadIdx.x >> 6, lane = threadIdx.x & 63;
  int l16 = lane & 15, quad = lane >> 4;
  int ti = blockIdx.x;
  int i0 = ti * 64 + w * 16;
  bf16x8 a0 = ld8(xb + (i0 + l16) * 64 + quad * 8);
  bf16x8 a1 = ld8(xb + (i0 + l16) * 64 + 32 + quad * 8);
  float sqi[4];
#pragma unroll
  for (int r = 0; r < 4; ++r) sqi[r] = sq[i0 + quad * 4 + r];
  float m = 0.f;
  const int jbase = blockIdx.y * 256;
#pragma unroll
  for (int jb = 0; jb < 4; ++jb) {
    int j0 = jbase + jb * 64;
#pragma unroll
    for (int jt = 0; jt < 4; ++jt) {
      int jr = j0 + jt * 16 + l16;
      bf16x8 b0 = ld8(xb + jr * 64 + quad * 8);
      bf16x8 b1 = ld8(xb + jr * 64 + 32 + quad * 8);
      f32x4 g = {0.f, 0.f, 0.f, 0.f};
      g = mfma16(a0, b0, g);
      g = mfma16(a1, b1, g);
      float sj = sq[jr];
#pragma unroll
      for (int r = 0; r < 4; ++r) m = fmaxf(m, fmaf(-2.f, g[r], sqi[r] + sj));
    }
  }
  m = fmaxf(m, 0.f);
#pragma unroll
  for (int o = 1; o < 64; o <<= 1) m = fmaxf(m, __shfl_xor(m, o));
  if (lane == 0) red[w] = m;
  __syncthreads();
  if (threadIdx.x == 0) {
    m = fmaxf(fmaxf(red[0], red[1]), fmaxf(red[2], red[3]));
    atomicMax((int*)&maxslots[ti * 16], __float_as_int(m));
  }
}

// ---------------- pass2: alpha weights + mu numerator partials ----------------
__global__ __launch_bounds__(256) void pass2_kernel(
    const u16* __restrict__ xb, const u16* __restrict__ xT, const float* __restrict__ sq,
    const float* __restrict__ maxslots, const float* __restrict__ r0in,
    float* __restrict__ mu_part, float* __restrict__ s_part) {
  __shared__ u16 ldsw[2][64 * LDW];
  __shared__ float sred[4][64];
  const int tid = threadIdx.x, w = tid >> 6, lane = tid & 63;
  const int l16 = lane & 15, quad = lane >> 4;
  const int j0 = blockIdx.x * 64;
  const int ibase = blockIdx.y * 256;

  float md = 0.f;
#pragma unroll
  for (int k = 0; k < 64; ++k) md = fmaxf(md, maxslots[k * 16]);
  const float r0c = fminf(r0in[0], fast_sqrt(md));
  const float r0sq = r0c * r0c;
  const float invr0sq = 1.f / r0sq;

  float sqj[4];
  bf16x8 xj[4][2];
#pragma unroll
  for (int jt = 0; jt < 4; ++jt) {
    int jr = j0 + jt * 16 + l16;
    sqj[jt] = sq[jr];
    xj[jt][0] = ld8(xb + jr * 64 + quad * 8);
    xj[jt][1] = ld8(xb + jr * 64 + 32 + quad * 8);
  }
  f32x4 zero4 = {0.f, 0.f, 0.f, 0.f};
  f32x4 acc[4];
#pragma unroll
  for (int pt = 0; pt < 4; ++pt) acc[pt] = zero4;
  float sa[4] = {0.f, 0.f, 0.f, 0.f};

#pragma unroll
  for (int s = 0; s < 4; ++s) {
    u16* buf = &ldsw[s & 1][0];
    const int ib = ibase + s * 64;
    const int ir = ib + w * 16;
    bf16x8 a0 = ld8(xb + (ir + l16) * 64 + quad * 8);
    bf16x8 a1 = ld8(xb + (ir + l16) * 64 + 32 + quad * 8);
    float sqi[4];
#pragma unroll
    for (int r = 0; r < 4; ++r) sqi[r] = sq[ir + quad * 4 + r];
    // pair-hoisted Gram MFMAs for ILP
#pragma unroll
    for (int jp = 0; jp < 2; ++jp) {
      const int jt0 = jp * 2, jt1 = jp * 2 + 1;
      f32x4 g0 = zero4, g1 = zero4;
      g0 = mfma16(a0, xj[jt0][0], g0);
      g1 = mfma16(a0, xj[jt1][0], g1);
      g0 = mfma16(a1, xj[jt0][1], g0);
      g1 = mfma16(a1, xj[jt1][1], g1);
      u16x4 pk0, pk1;
#pragma unroll
      for (int r = 0; r < 4; ++r) {
        float d2a = fmaxf(fmaf(-2.f, g0[r], sqi[r] + sqj[jt0]), 0.f);
        float ba = fmaxf(fmaf(-d2a, invr0sq, 1.f), 0.f);
        float wa = ba * ba * ba;
        sa[jt0] += wa;
        pk0[r] = f2bf_t(wa);
        float d2b = fmaxf(fmaf(-2.f, g1[r], sqi[r] + sqj[jt1]), 0.f);
        float bb = fmaxf(fmaf(-d2b, invr0sq, 1.f), 0.f);
        float wb = bb * bb * bb;
        sa[jt1] += wb;
        pk1[r] = f2bf_t(wb);
      }
      *reinterpret_cast<u16x4*>(&buf[(jt0 * 16 + l16) * LDW + w * 16 + quad * 4]) = pk0;
      *reinterpret_cast<u16x4*>(&buf[(jt1 * 16 + l16) * LDW + w * 16 + quad * 4]) = pk1;
    }
    __syncthreads();
    bf16x8 aw0 = *reinterpret_cast<const bf16x8*>(&buf[(w * 16 + l16) * LDW + quad * 8]);
    bf16x8 aw1 = *reinterpret_cast<const bf16x8*>(&buf[(w * 16 + l16) * LDW + 32 + quad * 8]);
#pragma unroll
    for (int pt = 0; pt < 4; ++pt) {
      const u16* xp = xT + (pt * 16 + l16) * NROW + ib + quad * 8;
      acc[pt] = mfma16(aw0, ld8(xp), acc[pt]);
      acc[pt] = mfma16(aw1, ld8(xp + 32), acc[pt]);
    }
  }
  float* mp = mu_part + (size_t)blockIdx.y * SLICE;
#pragma unroll
  for (int pt = 0; pt < 4; ++pt)
#pragma unroll
    for (int r = 0; r < 4; ++r)
      mp[(j0 + w * 16 + quad * 4 + r) * 64 + pt * 16 + l16] = acc[pt][r];
#pragma unroll
  for (int jt = 0; jt < 4; ++jt) {
    float v = sa[jt];
    v += __shfl_xor(v, 16);
    v += __shfl_xor(v, 32);
    if (lane < 16) sred[w][jt * 16 + lane] = v;
  }
  __syncthreads();
  if (tid < 64)
    s_part[blockIdx.y * NROW + j0 + tid] =
        sred[0][tid] + sred[1][tid] + sred[2][tid] + sred[3][tid];
}

// ---------------- finish_mu: float4 reduce partials; U, ||U||^2, t ----------------
__global__ __launch_bounds__(256) void finish_mu_kernel(
    const float* __restrict__ x, const float* __restrict__ mu_part,
    const float* __restrict__ s_part, u16* __restrict__ ub, float* __restrict__ un2,
    float* __restrict__ tvec) {
  const int tid = threadIdx.x;
  const int row = blockIdx.x * 16 + (tid >> 4);
  const int c4 = tid & 15;
  float4 num = {0.f, 0.f, 0.f, 0.f};
  float den = 0.f;
#pragma unroll
  for (int y = 0; y < NSPLIT; ++y) {
    float4 v = *reinterpret_cast<const float4*>(&mu_part[(size_t)y * SLICE + row * 64 + c4 * 4]);
    num.x += v.x; num.y += v.y; num.z += v.z; num.w += v.w;
    den += s_part[y * NROW + row];
  }
  float4 xv = *reinterpret_cast<const float4*>(&x[row * 64 + c4 * 4]);
  float inv = 1.f / den;
  float m0 = num.x * inv, m1 = num.y * inv, m2 = num.z * inv, m3 = num.w * inv;
  if (m0 != m0) m0 = xv.x;
  if (m1 != m1) m1 = xv.y;
  if (m2 != m2) m2 = xv.z;
  if (m3 != m3) m3 = xv.w;
  float U0 = xv.x - m0, U1 = xv.y - m1, U2 = xv.z - m2, U3 = xv.w - m3;
  u16x4 pb;
  pb[0] = f2bf(U0); pb[1] = f2bf(U1); pb[2] = f2bf(U2); pb[3] = f2bf(U3);
  *reinterpret_cast<u16x4*>(&ub[row * 64 + c4 * 4]) = pb;
  float a = U0 * U0 + U1 * U1 + U2 * U2 + U3 * U3;
  float b = xv.x * U0 + xv.y * U1 + xv.z * U2 + xv.w * U3;
#pragma unroll
  for (int o = 1; o < 16; o <<= 1) {
    a += __shfl_xor(a, o);
    b += __shfl_xor(b, o);
  }
  if (c4 == 0) {
    un2[row] = a;
    tvec[row] = b;
  }
}

// ---------------- pass3: beta weights + e_Z numerator partials ----------------
__global__ __launch_bounds__(256) void pass3_kernel(
    const u16* __restrict__ xb, const u16* __restrict__ xT, const u16* __restrict__ ub,
    const float* __restrict__ sq, const float* __restrict__ tvec, const float* __restrict__ un2,
    const float* __restrict__ maxslots, const float* __restrict__ r1in,
    const float* __restrict__ r2in, float* __restrict__ ez_part, float* __restrict__ s_part) {
  __shared__ u16 ldsw[2][64 * LDW];
  __shared__ float sred[4][64];
  const int tid = threadIdx.x, w = tid >> 6, lane = tid & 63;
  const int l16 = lane & 15, quad = lane >> 4;
  const int j0 = blockIdx.x * 64;
  const int ibase = blockIdx.y * 256;

  float md = 0.f;
#pragma unroll
  for (int k = 0; k < 64; ++k) md = fmaxf(md, maxslots[k * 16]);
  const float mdist = fast_sqrt(md);
  const float r1c = fminf(r1in[0], mdist);
  const float r2c = fminf(r2in[0], mdist);
  const float i1x2 = 2.f / r1c;
  const float i2x2 = 2.f / r2c;

  float sqj[4], tj[4], u2j[4];
  bf16x8 xj[4][2], uj[4][2];
#pragma unroll
  for (int jt = 0; jt < 4; ++jt) {
    int jr = j0 + jt * 16 + l16;
    sqj[jt] = sq[jr];
    tj[jt] = tvec[jr];
    u2j[jt] = un2[jr];
    xj[jt][0] = ld8(xb + jr * 64 + quad * 8);
    xj[jt][1] = ld8(xb + jr * 64 + 32 + quad * 8);
    uj[jt][0] = ld8(ub + jr * 64 + quad * 8);
    uj[jt][1] = ld8(ub + jr * 64 + 32 + quad * 8);
  }
  f32x4 zero4 = {0.f, 0.f, 0.f, 0.f};
  f32x4 acc[4];
#pragma unroll
  for (int pt = 0; pt < 4; ++pt) acc[pt] = zero4;
  float sb[4] = {0.f, 0.f, 0.f, 0.f};

#pragma unroll
  for (int s = 0; s < 4; ++s) {
    u16* buf = &ldsw[s & 1][0];
    const int ib = ibase + s * 64;
    const int ir = ib + w * 16;
    bf16x8 a0 = ld8(xb + (ir + l16) * 64 + quad * 8);
    bf16x8 a1 = ld8(xb + (ir + l16) * 64 + 32 + quad * 8);
    float sqi[4];
#pragma unroll
    for (int r = 0; r < 4; ++r) sqi[r] = sq[ir + quad * 4 + r];
#pragma unroll
    for (int jt = 0; jt < 4; ++jt) {
      f32x4 gxx = zero4, gxu = zero4;
      gxx = mfma16(a0, xj[jt][0], gxx);
      gxu = mfma16(a0, uj[jt][0], gxu);
      gxx = mfma16(a1, xj[jt][1], gxx);
      gxu = mfma16(a1, uj[jt][1], gxu);
      const float tjv = tj[jt], u2jv = u2j[jt], sjv = sqj[jt];
      u16x4 pk;
#pragma unroll
      for (int r = 0; r < 4; ++r) {
        float d2 = fmaxf(fmaf(-2.f, gxx[r], sqi[r] + sjv), 0.f);
        float c = gxu[r] - tjv;
        float du2 = fmaxf(c * c * u2jv, 1e-6f);
        float dv2 = fmaxf(d2 - du2, 1e-6f);
        float du = fast_sqrt(du2);
        float dv = fast_sqrt(dv2);
        // w(d) = (1 - t^2)^3, t = clamp(2d/r - 1, 0, 1): exact on all 3 branches
        float q1 = fminf(fmaxf(fmaf(dv, i1x2, -1.f), 0.f), 1.f);
        float b1 = fmaf(-q1, q1, 1.f);
        float w1 = b1 * b1 * b1;
        float q2 = fminf(fmaxf(fmaf(du, i2x2, -1.f), 0.f), 1.f);
        float b2 = fmaf(-q2, q2, 1.f);
        float w2 = b2 * b2 * b2;
        float wv = w1 * w2;
        sb[jt] += wv;
        pk[r] = f2bf_t(wv);
      }
      *reinterpret_cast<u16x4*>(&buf[(jt * 16 + l16) * LDW + w * 16 + quad * 4]) = pk;
    }
    __syncthreads();
    bf16x8 aw0 = *reinterpret_cast<const bf16x8*>(&buf[(w * 16 + l16) * LDW + quad * 8]);
    bf16x8 aw1 = *reinterpret_cast<const bf16x8*>(&buf[(w * 16 + l16) * LDW + 32 + quad * 8]);
#pragma unroll
    for (int pt = 0; pt < 4; ++pt) {
      const u16* xp = xT + (pt * 16 + l16) * NROW + ib + quad * 8;
      acc[pt] = mfma16(aw0, ld8(xp), acc[pt]);
      acc[pt] = mfma16(aw1, ld8(xp + 32), acc[pt]);
    }
  }
  float* ep = ez_part + (size_t)blockIdx.y * SLICE;
#pragma unroll
  for (int pt = 0; pt < 4; ++pt)
#pragma unroll
    for (int r = 0; r < 4; ++r)
      ep[(j0 + w * 16 + quad * 4 + r) * 64 + pt * 16 + l16] = acc[pt][r];
#pragma unroll
  for (int jt = 0; jt < 4; ++jt) {
    float v = sb[jt];
    v += __shfl_xor(v, 16);
    v += __shfl_xor(v, 32);
    if (lane < 16) sred[w][jt * 16 + lane] = v;
  }
  __syncthreads();
  if (tid < 64)
    s_part[blockIdx.y * NROW + j0 + tid] =
        sred[0][tid] + sred[1][tid] + sred[2][tid] + sred[3][tid];
}

// ---------------- finish: float4 reduce partials, NaN -> x ----------------
__global__ __launch_bounds__(256) void finish_kernel(const float* __restrict__ x,
                                                     const float* __restrict__ ez_part,
                                                     const float* __restrict__ s_part,
                                                     float* __restrict__ out) {
  const int tid = threadIdx.x;
  const int row = blockIdx.x * 16 + (tid >> 4);
  const int c4 = tid & 15;
  float4 num = {0.f, 0.f, 0.f, 0.f};
  float den = 0.f;
#pragma unroll
  for (int y = 0; y < NSPLIT; ++y) {
    float4 v = *reinterpret_cast<const float4*>(&ez_part[(size_t)y * SLICE + row * 64 + c4 * 4]);
    num.x += v.x; num.y += v.y; num.z += v.z; num.w += v.w;
    den += s_part[y * NROW + row];
  }
  float4 xv = *reinterpret_cast<const float4*>(&x[row * 64 + c4 * 4]);
  float inv = 1.f / den;
  float4 o;
  o.x = num.x * inv; o.y = num.y * inv; o.z = num.z * inv; o.w = num.w * inv;
  if (o.x != o.x) o.x = xv.x;
  if (o.y != o.y) o.y = xv.y;
  if (o.z != o.z) o.z = xv.z;
  if (o.w != o.w) o.w = xv.w;
  *reinterpret_cast<float4*>(&out[row * 64 + c4 * 4]) = o;
}

extern "C" void kernel_launch(void* const* d_in, const int* in_sizes, int n_in,
                              void* d_out, int out_size, void* d_ws, size_t ws_size,
                              hipStream_t stream) {
  (void)in_sizes; (void)n_in; (void)out_size;
  const float* x = (const float*)d_in[0];
  const float* r0 = (const float*)d_in[1];
  const float* r1 = (const float*)d_in[2];
  const float* r2 = (const float*)d_in[3];
  float* out = (float*)d_out;
  char* ws = (char*)d_ws;

  u16* xb = (u16*)(ws);                              // 512 KB
  u16* xT = (u16*)(ws + (512 << 10));                // 512 KB
  u16* ub = (u16*)(ws + (1024 << 10));               // 512 KB
  float* sq = (float*)(ws + (1536 << 10));           // 16 KB
  float* tv = (float*)(ws + (1552 << 10));           // 16 KB
  float* u2 = (float*)(ws + (1568 << 10));           // 16 KB
  float* maxslots = (float*)(ws + (1584 << 10));     // 4 KB
  float* s_part_a = (float*)(ws + (1588 << 10));     // 256 KB
  float* s_part_b = (float*)(ws + (1844 << 10));     // 256 KB
  float* part = (float*)(ws + (2100 << 10));         // 16 MB (aliased mu/ez partials)
  size_t need = ((size_t)2100 << 10) + ((size_t)16 << 20);
  if (ws_size < need) return;

  prep_kernel<<<64, 256, 0, stream>>>(x, xb, xT, sq, maxslots);
  pass1_max<<<dim3(64, 16), 256, 0, stream>>>(xb, sq, maxslots);
  pass2_kernel<<<dim3(64, NSPLIT), 256, 0, stream>>>(xb, xT, sq, maxslots, r0, part, s_part_a);
  finish_mu_kernel<<<256, 256, 0, stream>>>(x, part, s_part_a, ub, u2, tv);
  pass3_kernel<<<dim3(64, NSPLIT), 256, 0, stream>>>(xb, xT, ub, sq, tv, u2, maxslots, r1, r2,
                                                     part, s_part_b);
  finish_kernel<<<256, 256, 0, stream>>>(x, part, s_part_b, out);
}